// Round 10
// baseline (381.376 us; speedup 1.0000x reference)
//
#include <hip/hip_runtime.h>
#include <hip/hip_bf16.h>
#include <math.h>

#define GLOBAL_AS __attribute__((address_space(1)))
#define LDS_AS __attribute__((address_space(3)))

typedef __bf16 bf16x8 __attribute__((ext_vector_type(8)));
typedef float f32x4 __attribute__((ext_vector_type(4)));

#define N 8192
#define D 1024

__device__ __forceinline__ unsigned short f2bf_rne(float f) {
  unsigned u = __float_as_uint(f);
  unsigned r = u + 0x7FFFu + ((u >> 16) & 1u);
  return (unsigned short)(r >> 16);
}

// Convert z (fp32) -> z_hi + z_lo (bf16 split), and row sums of squares.
// zh and zl adjacent => [N][2048] extended bf16 matrix, gram ~= fp32 gram.
__global__ __launch_bounds__(256) void prep_kernel(
    const float* __restrict__ z, unsigned short* __restrict__ zh,
    unsigned short* __restrict__ zl, float* __restrict__ sq) {
  const int r = blockIdx.x, t = threadIdx.x;
  const float4 v = *(const float4*)(z + (size_t)r * D + t * 4);
  float f[4] = {v.x, v.y, v.z, v.w};
  unsigned short hh[4], ll[4];
  float s = 0.f;
#pragma unroll
  for (int u = 0; u < 4; ++u) {
    float x = f[u];
    s = fmaf(x, x, s);
    unsigned short hb = f2bf_rne(x);
    float hf = __uint_as_float(((unsigned)hb) << 16);
    hh[u] = hb;
    ll[u] = f2bf_rne(x - hf);
  }
  *(ushort4*)(zh + (size_t)r * D + t * 4) = make_ushort4(hh[0], hh[1], hh[2], hh[3]);
  *(ushort4*)(zl + (size_t)r * D + t * 4) = make_ushort4(ll[0], ll[1], ll[2], ll[3]);
#pragma unroll
  for (int o = 32; o >= 1; o >>= 1) s += __shfl_down(s, o, 64);
  __shared__ float red[4];
  const int lane = t & 63, wv = t >> 6;
  if (lane == 0) red[wv] = s;
  __syncthreads();
  if (t == 0) sq[r] = ((red[0] + red[1]) + red[2]) + red[3];
}

// ------- 256x256-tile gram, TWO 256x128 j-half passes, 8-phase, BK=64 -----
// 8 waves (2M x 4N); per-wave output 128x32 -> acc[8][2] = 64 f32.
// Why halved: an 8-wave block is co-resident => hard 256-reg/wave ceiling;
// r8/r9's acc[8][4]=128 + frags + temps > 256 => structural scratch spill
// (184 MB writes). This geometry's live set ~130 regs: cannot spill.
// Per K-tile (48KB): A chunks 0-3 (256rx64c), B chunks 0-1 (128rx64c);
// chunk = 8KB = one global_load_lds (512 thr x 16B). dbuf bufs at 0/49152.
// Phases per iter (2 K-tiles): ph1-4 = buf0 (qm,kc), ph5-8 = buf1.
// Staging (12 chunks/iter), waits ONE PHASE BEFORE the reads they cover:
//   ph1: odd{A1,A3}  ph2: odd{B0,B1}  ph3: nxt0{A0,A2}  ph4: WVM(2)
//   ph5: nxt0{A1,A3} ph6: nxt0{B0,B1} ph7: nxt1{A0,A2}  ph8: WVM(2)
// Writes always chunk-disjoint from concurrent readers (audited per phase).
// Swizzle (0-conflict, r5-r8): LDS unit (row,cs) holds global unit
// cs^(row&7); read unit (kc*4+kg)^(r0&7) -> kc flips byte bit6.
#define WVM(NN) asm volatile("s_waitcnt vmcnt(" #NN ")" ::: "memory")
#define NOOP ((void)0)

#define STG(BUF, CH, TOFFV)                                                     \
  __builtin_amdgcn_global_load_lds(                                             \
      (const GLOBAL_AS void*)((((CH) < 4) ? (aBase + (CH) * 131072)             \
                                          : (bBaseH + ((CH) - 4) * 131072)) +   \
                              (TOFFV) + vstage),                                \
      (LDS_AS void*)(ldsc + (BUF) * 49152 +                                     \
                     (((CH) < 4) ? (CH) * 8192 : 32768 + ((CH) - 4) * 8192) +   \
                     tid * 16),                                                 \
      16, 0, 0)

#define MF(MM, AA, NN, BB) \
  acc[MM][NN] = __builtin_amdgcn_mfma_f32_16x16x32_bf16(AA, BB, acc[MM][NN], 0, 0, 0)

#define PH(BUFOFF, QM, KC, STAGES, WAITS)                 \
  {                                                       \
    const char* Ab_ = ldsc + (BUFOFF) + Aw + (QM) * 8192; \
    const char* Bb_ = ldsc + (BUFOFF) + Bw;               \
    const unsigned ro_ = arow ^ ((KC) * 64u);             \
    bf16x8 a0_ = *(const bf16x8*)(Ab_ + ro_);             \
    bf16x8 a1_ = *(const bf16x8*)(Ab_ + 2048 + ro_);      \
    bf16x8 a2_ = *(const bf16x8*)(Ab_ + 4096 + ro_);      \
    bf16x8 a3_ = *(const bf16x8*)(Ab_ + 6144 + ro_);      \
    bf16x8 b0_ = *(const bf16x8*)(Bb_ + ro_);             \
    bf16x8 b1_ = *(const bf16x8*)(Bb_ + 2048 + ro_);      \
    STAGES;                                               \
    WAITS;                                                \
    __builtin_amdgcn_s_barrier();                         \
    __builtin_amdgcn_s_setprio(1);                        \
    MF((QM) * 4 + 0, a0_, 0, b0_);                        \
    MF((QM) * 4 + 0, a0_, 1, b1_);                        \
    MF((QM) * 4 + 1, a1_, 0, b0_);                        \
    MF((QM) * 4 + 1, a1_, 1, b1_);                        \
    MF((QM) * 4 + 2, a2_, 0, b0_);                        \
    MF((QM) * 4 + 2, a2_, 1, b1_);                        \
    MF((QM) * 4 + 3, a3_, 0, b0_);                        \
    MF((QM) * 4 + 3, a3_, 1, b1_);                        \
    __builtin_amdgcn_s_setprio(0);                        \
    __builtin_amdgcn_s_barrier();                         \
  }

__global__ __launch_bounds__(512, 1) void gram_kernel(
    const unsigned short* __restrict__ zh,
    const float* __restrict__ sq, const int* __restrict__ idx,
    float* __restrict__ Pws, float* __restrict__ Pz, float* __restrict__ Ppl) {
  // LDS: bufs [0,98304) | comb_d 12288B | comb_t 1536B | lut 96B
  __shared__ __align__(16) char ldsall[98304 + 12288 + 1536 + 96];
  char* ldsc = ldsall;
  float* comb_d = (float*)(ldsall + 98304);           // [wave][128 rows][3]
  float* comb_t = (float*)(ldsall + 98304 + 12288);   // [(wc*2+n)*16+r0][3]
  float2* lut = (float2*)(ldsall + 98304 + 12288 + 1536);

  // XCD-bijective chunked swizzle (528 % 8 == 0)
  int bid = (int)blockIdx.x;
  bid = (bid & 7) * 66 + (bid >> 3);
  // triangle decode: bid = ib*(ib+1)/2 + jb, jb <= ib, ib < 32
  int ibv = (int)((sqrtf(8.f * (float)bid + 1.f) - 1.f) * 0.5f);
  while ((ibv + 1) * (ibv + 2) / 2 <= bid) ++ibv;
  while (ibv * (ibv + 1) / 2 > bid) --ibv;
  const int ib = __builtin_amdgcn_readfirstlane(ibv);
  const int jb = __builtin_amdgcn_readfirstlane(bid - ibv * (ibv + 1) / 2);

  const int tid = threadIdx.x;
  const int lane = tid & 63, wv = tid >> 6;  // 8 waves
  const int wr = wv >> 2, wc = wv & 3;       // 2(M) x 4(N)
  const int r0 = lane & 15, kg = lane >> 4;

  if (tid < 12) {
    const float Pl = (tid == 11) ? 0.f : -2.f * exp2f(-1.5849625007211562f * (float)tid);
    const float w = exp2f(1.4426950408889634f * Pl);
    lut[tid] = make_float2(w, w * Pl);
  }

  // staging: thread t -> chunk-row t>>3 (64 rows), unit col t&7, pre-swizzled
  const unsigned vstage =
      ((unsigned)(tid >> 3) * 2048u) + ((unsigned)((tid & 7) ^ ((tid >> 3) & 7)) * 16u);
  const char* aBase = (const char*)zh + (size_t)ib * 524288;  // 256 rows * 2048B
  const char* bBase = (const char*)zh + (size_t)jb * 524288;
  const size_t SEGOFF = (size_t)N * D * 2;  // hi-half -> lo-half bytes
#define TOFF(T) ((size_t)((T) >> 4) * SEGOFF + (unsigned)(((T) & 15) * 128))

  // LDS read addressing
  const unsigned arow = (unsigned)(r0 * 128 + ((kg ^ (r0 & 7)) * 16));
  const unsigned Aw = (unsigned)(wr * 2) * 8192u;                      // A chunk wr*2+qm
  const unsigned Bw = 32768u + (unsigned)(wc >> 1) * 8192u + (unsigned)(wc & 1) * 4096u;

#pragma unroll 1
  for (int h = 0; h < 2; ++h) {
    const char* bBaseH = bBase + h * 262144;  // 128 rows * 2048B per half

    f32x4 acc[8][2];
    const f32x4 vz = {0.f, 0.f, 0.f, 0.f};
#pragma unroll
    for (int m = 0; m < 8; ++m) {
      acc[m][0] = vz;
      acc[m][1] = vz;
    }

    {  // prologue: tile0 all 6 chunks -> buf0; tile1 {A0,A2} -> buf1
      const size_t o0 = TOFF(0), o1 = TOFF(1);
      STG(0, 0, o0); STG(0, 1, o0); STG(0, 2, o0); STG(0, 3, o0);
      STG(0, 4, o0); STG(0, 5, o0);
      STG(1, 0, o1); STG(1, 2, o1);
      WVM(2);
      __builtin_amdgcn_s_barrier();
    }

#pragma unroll 1
    for (int i = 0; i < 15; ++i) {
      const size_t o1 = TOFF(2 * i + 1), o2 = TOFF(2 * i + 2), o3 = TOFF(2 * i + 3);
      PH(0,     0, 0, { STG(1, 1, o1); STG(1, 3, o1); }, NOOP);
      PH(0,     0, 1, { STG(1, 4, o1); STG(1, 5, o1); }, NOOP);
      PH(0,     1, 0, { STG(0, 0, o2); STG(0, 2, o2); }, NOOP);
      PH(0,     1, 1, NOOP, WVM(2));   // odd tile fully landed before ph5 reads
      PH(49152, 0, 0, { STG(0, 1, o2); STG(0, 3, o2); }, NOOP);
      PH(49152, 0, 1, { STG(0, 4, o2); STG(0, 5, o2); }, NOOP);
      PH(49152, 1, 0, { STG(1, 0, o3); STG(1, 2, o3); }, NOOP);
      PH(49152, 1, 1, NOOP, WVM(2));   // next even tile landed before next ph1
    }
    {  // peeled last iteration: tiles 30 (buf0), 31 (buf1)
      const size_t o1 = TOFF(31);
      PH(0,     0, 0, { STG(1, 1, o1); STG(1, 3, o1); }, NOOP);
      PH(0,     0, 1, { STG(1, 4, o1); STG(1, 5, o1); }, NOOP);
      PH(0,     1, 0, NOOP, NOOP);
      PH(0,     1, 1, NOOP, WVM(0));
      PH(49152, 0, 0, NOOP, NOOP);
      PH(49152, 0, 1, NOOP, NOOP);
      PH(49152, 1, 0, NOOP, NOOP);
      PH(49152, 1, 1, NOOP, NOOP);
    }

    // ---- epilogue for this half ----
    const int jbase = jb * 256 + h * 128 + wc * 32 + r0;
    const int ibase = ib * 256 + wr * 128 + kg * 4;
    float sqj[2];
    int idxj[2];
#pragma unroll
    for (int n = 0; n < 2; ++n) {
      sqj[n] = sq[jbase + n * 16];
      idxj[n] = idx[jbase + n * 16];
    }
    float cws[2] = {0.f, 0.f}, czz[2] = {0.f, 0.f}, cpl[2] = {0.f, 0.f};
#pragma unroll
    for (int m = 0; m < 8; ++m) {
#pragma unroll
      for (int q = 0; q < 4; ++q) {
        const int i = ibase + m * 16 + q;
        const float sqi = sq[i];
        const int idxi = idx[i];
        float ws = 0.f, zz = 0.f, wpl = 0.f;
#pragma unroll
        for (int n = 0; n < 2; ++n) {
          const int j = jbase + n * 16;
          const float g = acc[m][n][q];
          const float d2 = sqi + sqj[n] - 2.f * g;
          const float dd = sqrtf(fmaxf(d2, 0.f));
          const float S = (i == j) ? 0.f : -2.f * dd;
          const int di = idxi - idxj[n];
          const unsigned diff = (unsigned)(di < 0 ? -di : di);
          // v3 via modular-inverse divisibility: /243(+5), /27(+3), /3, /3
          unsigned dq = diff, qq;
          int vvv = 0;
          qq = dq * 3534952507u; { const bool b = qq <= 17674762u;   dq = b ? qq : dq; vvv += b ? 5 : 0; }
          qq = dq * 1749801491u; { const bool b = qq <= 159072862u;  dq = b ? qq : dq; vvv += b ? 3 : 0; }
          qq = dq * 2863311531u; { const bool b = qq <= 1431655765u; dq = b ? qq : dq; vvv += b ? 1 : 0; }
          qq = dq * 2863311531u; { const bool b = qq <= 1431655765u; vvv += b ? 1 : 0; }
          vvv = (diff == 0u) ? 11 : vvv;
          const float2 wt = lut[vvv];
          const float wS = wt.x * S;
          ws += wS; zz += wt.x; wpl += wt.y;
          cws[n] += wS; czz[n] += wt.x; cpl[n] += wt.y;
        }
#pragma unroll
        for (int o = 1; o < 16; o <<= 1) {
          ws += __shfl_xor(ws, o, 64);
          zz += __shfl_xor(zz, o, 64);
          wpl += __shfl_xor(wpl, o, 64);
        }
        if (r0 == 0) {  // post per-wave row partial (32 cols) for pass 2
          float* p = comb_d + (wv * 128 + m * 16 + kg * 4 + q) * 3;
          p[0] = ws; p[1] = zz; p[2] = wpl;
        }
      }
    }
    // transposed (column) sums: reduce over kg groups in-wave; wr=1 posts
    float ta[2], tb[2], tc[2];
    if (ib != jb) {
#pragma unroll
      for (int n = 0; n < 2; ++n) {
        float a = cws[n], b = czz[n], c = cpl[n];
#pragma unroll
        for (int o = 16; o < 64; o <<= 1) {
          a += __shfl_xor(a, o, 64);
          b += __shfl_xor(b, o, 64);
          c += __shfl_xor(c, o, 64);
        }
        ta[n] = a; tb[n] = b; tc[n] = c;
        if (wr == 1 && kg == 0) {
          float* p = comb_t + ((wc * 2 + n) * 16 + r0) * 3;
          p[0] = a; p[1] = b; p[2] = c;
        }
      }
    }
    __syncthreads();
    {  // pass 2 direct: 512 threads -> (strip p2, row) cells; combine wc-pair
      const int p2 = tid >> 8, row = tid & 255;
      const int wrr = row >> 7, rl = row & 127;
      const float* pa = comb_d + ((wrr * 4 + p2 * 2) * 128 + rl) * 3;
      const float* pb = comb_d + ((wrr * 4 + p2 * 2 + 1) * 128 + rl) * 3;
      const int dslot = jb * 4 + h * 2 + p2;
      const int i = ib * 256 + row;
      Pws[(size_t)dslot * N + i] = pa[0] + pb[0];
      Pz[(size_t)dslot * N + i] = pa[1] + pb[1];
      Ppl[(size_t)dslot * N + i] = pa[2] + pb[2];
    }
    if (ib != jb && wr == 0 && kg == 0) {  // pass 2 transposed: combine wr-pair
      const int tslot = ib * 4 + h * 2 + (wc >> 1);
#pragma unroll
      for (int n = 0; n < 2; ++n) {
        const float* p = comb_t + ((wc * 2 + n) * 16 + r0) * 3;
        const int j = jbase + n * 16;
        Pws[(size_t)tslot * N + j] = ta[n] + p[0];
        Pz[(size_t)tslot * N + j] = tb[n] + p[1];
        Ppl[(size_t)tslot * N + j] = tc[n] + p[2];
      }
    }
    // half-1 comb_d posts happen only after its k-loop's many barriers: safe
  }
}

// Per-row: combine the 128 j-partials (fixed order) -> T_i
__global__ __launch_bounds__(256) void r1_kernel(
    const float* __restrict__ Pws, const float* __restrict__ Pz,
    const float* __restrict__ Ppl, float* __restrict__ t) {
  const int row = blockIdx.x * 256 + threadIdx.x;
  float ws = 0.f, zz = 0.f, wpl = 0.f;
  for (int s = 0; s < 128; ++s) {
    ws += Pws[(size_t)s * N + row];
    zz += Pz[(size_t)s * N + row];
    wpl += Ppl[(size_t)s * N + row];
  }
  t[row] = (wpl - ws) / zz - logf(zz);
}

// Final deterministic scalar reduction.
__global__ __launch_bounds__(256) void r2_kernel(const float* __restrict__ t,
                                                 float* __restrict__ out) {
  __shared__ float red[256];
  float s = 0.f;
  for (int r = threadIdx.x; r < N; r += 256) s += t[r];
  red[threadIdx.x] = s;
  __syncthreads();
  for (int o = 128; o > 0; o >>= 1) {
    if (threadIdx.x < (unsigned)o) red[threadIdx.x] += red[threadIdx.x + o];
    __syncthreads();
  }
  if (threadIdx.x == 0) out[0] = red[0] / (float)N;
}

extern "C" void kernel_launch(void* const* d_in, const int* in_sizes, int n_in,
                              void* d_out, int out_size, void* d_ws, size_t ws_size,
                              hipStream_t stream) {
  const float* z = (const float*)d_in[0];
  const int* idx = (const int*)d_in[1];
  float* out = (float*)d_out;
  char* ws = (char*)d_ws;
  // workspace layout (~44.2 MB total); zh and zl MUST be adjacent (Kext view)
  unsigned short* zh = (unsigned short*)ws;                            // 16 MB
  unsigned short* zl = zh + (size_t)N * D;                             // 16 MB
  float* sq = (float*)(ws + ((size_t)32 << 20));                       // 32 KB
  float* Pws = (float*)(ws + ((size_t)32 << 20) + ((size_t)64 << 10)); // 4 MB
  float* Pz = Pws + (size_t)128 * N;                                   // 4 MB
  float* Ppl = Pz + (size_t)128 * N;                                   // 4 MB
  float* tt = Ppl + (size_t)128 * N;                                   // 32 KB

  prep_kernel<<<N, 256, 0, stream>>>(z, zh, zl, sq);
  gram_kernel<<<528, 512, 0, stream>>>(zh, sq, idx, Pws, Pz, Ppl);
  r1_kernel<<<N / 256, 256, 0, stream>>>(Pws, Pz, Ppl, tt);
  r2_kernel<<<1, 256, 0, stream>>>(tt, out);
}

// Round 11
// 257.882 us; speedup vs baseline: 1.4789x; 1.4789x over previous
//
#include <hip/hip_runtime.h>
#include <hip/hip_bf16.h>
#include <math.h>

#define GLOBAL_AS __attribute__((address_space(1)))
#define LDS_AS __attribute__((address_space(3)))

typedef __bf16 bf16x8 __attribute__((ext_vector_type(8)));
typedef float f32x4 __attribute__((ext_vector_type(4)));

#define N 8192
#define D 1024

__device__ __forceinline__ unsigned short f2bf_rne(float f) {
  unsigned u = __float_as_uint(f);
  unsigned r = u + 0x7FFFu + ((u >> 16) & 1u);
  return (unsigned short)(r >> 16);
}

// Convert z (fp32) -> z_hi + z_lo (bf16 split), and row sums of squares.
// zh and zl are adjacent: zl = zh + N*D, forming a [N][2048] "extended" bf16
// matrix whose gram = hi.hi + hi.lo + lo.hi + lo.lo ~= fp32 gram.
__global__ __launch_bounds__(256) void prep_kernel(
    const float* __restrict__ z, unsigned short* __restrict__ zh,
    unsigned short* __restrict__ zl, float* __restrict__ sq) {
  const int r = blockIdx.x, t = threadIdx.x;
  const float4 v = *(const float4*)(z + (size_t)r * D + t * 4);
  float f[4] = {v.x, v.y, v.z, v.w};
  unsigned short hh[4], ll[4];
  float s = 0.f;
#pragma unroll
  for (int u = 0; u < 4; ++u) {
    float x = f[u];
    s = fmaf(x, x, s);
    unsigned short hb = f2bf_rne(x);
    float hf = __uint_as_float(((unsigned)hb) << 16);
    hh[u] = hb;
    ll[u] = f2bf_rne(x - hf);
  }
  *(ushort4*)(zh + (size_t)r * D + t * 4) = make_ushort4(hh[0], hh[1], hh[2], hh[3]);
  *(ushort4*)(zl + (size_t)r * D + t * 4) = make_ushort4(ll[0], ll[1], ll[2], ll[3]);
  // deterministic block reduction
#pragma unroll
  for (int o = 32; o >= 1; o >>= 1) s += __shfl_down(s, o, 64);
  __shared__ float red[4];
  const int lane = t & 63, wv = t >> 6;
  if (lane == 0) red[wv] = s;
  __syncthreads();
  if (t == 0) sq[r] = ((red[0] + red[1]) + red[2]) + red[3];
}

// Lower-triangle 128x128 tile gram over Kext=2048, BK=64, fused KL epilogue.
// This is EXACTLY the round-6 kernel (best measured: 223us even while
// spilling 114MB) with the one defect removed: launch_bounds(256,3)'s
// 170-reg cap left ~106 arch regs vs the ~112 the loop needs (64 AGPR acc
// consume the rest) -> ~1.7 dword/iter scratch round-trip. (256,2) = 256-reg
// cap; r5 proved this loop family runs spill-free there (112 arch VGPR).
// Occupancy 2 blocks/CU (8 waves) instead of 3 - the spill removal is worth
// more than the third block (r5 vs r6 delta was sync-structure, not TLP).
//
// 512-thread/8-wave variants (r8-r10) are abandoned: an 8-wave block is
// hard-capped at 256 unified regs/wave (co-residency) and the compiler
// spills ~150MB there regardless of acc size - structural, unexplained,
// three strikes.
//
// Swizzle: LDS unit (rr, cs) holds global unit (rr, cs ^ (rr&7)); read at
// unit (kc*4+kg)^(r0&7) -> 8 lanes per bank-group, conflict-free (measured
// 0 conflicts r5-r10).
__global__ __launch_bounds__(256, 2) void gram_kernel(
    const unsigned short* __restrict__ zh,
    const float* __restrict__ sq, const int* __restrict__ idx,
    float* __restrict__ Pws, float* __restrict__ Pz, float* __restrict__ Ppl) {
  __shared__ __align__(16) unsigned short lds[2 * 128 * 64];  // A, B (32 KiB)
  __shared__ float2 lut[12];  // (w, w*Pl) per v3 value; [11] = diff==0 case
  // triangle decode: blockIdx.x = ib*(ib+1)/2 + jb, jb <= ib
  const int t = blockIdx.x;
  int ibv = (int)((sqrtf(8.f * (float)t + 1.f) - 1.f) * 0.5f);
  while ((ibv + 1) * (ibv + 2) / 2 <= t) ++ibv;
  while (ibv * (ibv + 1) / 2 > t) --ibv;
  const int ib = __builtin_amdgcn_readfirstlane(ibv);
  const int jb = __builtin_amdgcn_readfirstlane(t - ibv * (ibv + 1) / 2);

  const int tid = threadIdx.x;
  const int lane = tid & 63, wv = tid >> 6;
  const int wr = wv >> 1, wc = wv & 1;
  const int r0 = lane & 15, kg = lane >> 4;

  if (tid < 12) {
    const float Pl = (tid == 11) ? 0.f : -2.f * exp2f(-1.5849625007211562f * (float)tid);
    const float w = exp2f(1.4426950408889634f * Pl);
    lut[tid] = make_float2(w, w * Pl);
  }

  // --- staging addressing (1 live VGPR) ---
  // inst i4 covers rows i4*32+(tid>>3); unit col cs = tid&7; source col unit
  // c = cs ^ (rr&7) (rr&7 == (tid>>3)&7, i4*32 = 0 mod 8).
  const unsigned vbase =
      ((unsigned)(tid >> 3) * 2048u) + ((unsigned)((tid & 7) ^ ((tid >> 3) & 7)) * 16u);
  const char* aBase = (const char*)(zh + (size_t)ib * 128 * D);
  const char* bBase = (const char*)(zh + (size_t)jb * 128 * D);
  char* ldsc = (char*)&lds[0];

  // --- LDS read addressing (2 live VGPRs; kc=1 = base ^ 64) ---
  const int ub = kg ^ (r0 & 3);          // unit bits 0..1
  const int kcx = (r0 >> 2) & 1;         // unit bit 2 xor source (row&4)
  const unsigned aoff0 = (unsigned)((wr * 64 + r0) * 128 + (kcx * 4 + ub) * 16);
  const unsigned boff0 = (unsigned)(16384 + (wc * 64 + r0) * 128 + (kcx * 4 + ub) * 16);

  f32x4 acc[4][4];
  const f32x4 vz = {0.f, 0.f, 0.f, 0.f};
#pragma unroll
  for (int m = 0; m < 4; ++m)
#pragma unroll
    for (int n = 0; n < 4; ++n) acc[m][n] = vz;

  // Kext = 2048: two segments (hi, lo) x 16 steps of BK=64 (128B)
#pragma unroll 1
  for (int seg = 0; seg < 2; ++seg) {
    const size_t segoff = (size_t)seg * ((size_t)N * D * 2);
#pragma unroll 1
    for (int ks = 0; ks < 16; ++ks) {
      const char* aS = aBase + segoff + (unsigned)(ks * 128);
      const char* bS = bBase + segoff + (unsigned)(ks * 128);
      __syncthreads();
#pragma unroll
      for (int i4 = 0; i4 < 4; ++i4)
        __builtin_amdgcn_global_load_lds(
            (const GLOBAL_AS void*)(aS + (unsigned)(i4 * 65536) + vbase),
            (LDS_AS void*)(ldsc + i4 * 4096 + tid * 16), 16, 0, 0);
#pragma unroll
      for (int i4 = 0; i4 < 4; ++i4)
        __builtin_amdgcn_global_load_lds(
            (const GLOBAL_AS void*)(bS + (unsigned)(i4 * 65536) + vbase),
            (LDS_AS void*)(ldsc + 16384 + i4 * 4096 + tid * 16), 16, 0, 0);
      __syncthreads();

      {  // kc = 0
        bf16x8 a[4], b[4];
#pragma unroll
        for (int m = 0; m < 4; ++m) a[m] = *(const bf16x8*)(ldsc + aoff0 + m * 2048);
#pragma unroll
        for (int n = 0; n < 4; ++n) b[n] = *(const bf16x8*)(ldsc + boff0 + n * 2048);
#pragma unroll
        for (int m = 0; m < 4; ++m)
#pragma unroll
          for (int n = 0; n < 4; ++n)
            acc[m][n] = __builtin_amdgcn_mfma_f32_16x16x32_bf16(a[m], b[n], acc[m][n], 0, 0, 0);
      }
      {  // kc = 1 (unit bit2 flip = byte bit6; row bits start at bit7)
        const unsigned aoff1 = aoff0 ^ 64u, boff1 = boff0 ^ 64u;
        bf16x8 a[4], b[4];
#pragma unroll
        for (int m = 0; m < 4; ++m) a[m] = *(const bf16x8*)(ldsc + aoff1 + m * 2048);
#pragma unroll
        for (int n = 0; n < 4; ++n) b[n] = *(const bf16x8*)(ldsc + boff1 + n * 2048);
#pragma unroll
        for (int m = 0; m < 4; ++m)
#pragma unroll
          for (int n = 0; n < 4; ++n)
            acc[m][n] = __builtin_amdgcn_mfma_f32_16x16x32_bf16(a[m], b[n], acc[m][n], 0, 0, 0);
      }
    }
  }

  // ---- Epilogue: S = -2*sqrt(max(sq_i+sq_j-2g,0)); padic weights; partials ----
  const int ibase = ib * 128 + wr * 64 + kg * 4;
  const int jbase = jb * 128 + wc * 64 + r0;
  float sqj[4];
  int idxj[4];
#pragma unroll
  for (int n = 0; n < 4; ++n) {
    sqj[n] = sq[jbase + n * 16];
    idxj[n] = idx[jbase + n * 16];
  }
  const int dslot = jb * 2 + wc;
  // column (transposed) accumulators: per n, summed over this lane's (m,q) i-set
  float cws[4] = {0.f, 0.f, 0.f, 0.f};
  float czz[4] = {0.f, 0.f, 0.f, 0.f};
  float cpl[4] = {0.f, 0.f, 0.f, 0.f};
#pragma unroll
  for (int m = 0; m < 4; ++m) {
#pragma unroll
    for (int q = 0; q < 4; ++q) {
      const int i = ibase + m * 16 + q;
      const float sqi = sq[i];
      const int idxi = idx[i];
      float ws = 0.f, zz = 0.f, wpl = 0.f;
#pragma unroll
      for (int n = 0; n < 4; ++n) {
        const int j = jbase + n * 16;
        const float g = acc[m][n][q];
        const float d2 = sqi + sqj[n] - 2.f * g;
        const float dd = sqrtf(fmaxf(d2, 0.f));
        const float S = (i == j) ? 0.f : -2.f * dd;
        const int di = idxi - idxj[n];
        const unsigned diff = (unsigned)(di < 0 ? -di : di);
        // v3 via modular-inverse divisibility: /243(+5), /27(+3), /3(+1), /3(+1)
        unsigned dq = diff, qq;
        int vvv = 0;
        qq = dq * 3534952507u; { const bool b = qq <= 17674762u;   dq = b ? qq : dq; vvv += b ? 5 : 0; }
        qq = dq * 1749801491u; { const bool b = qq <= 159072862u;  dq = b ? qq : dq; vvv += b ? 3 : 0; }
        qq = dq * 2863311531u; { const bool b = qq <= 1431655765u; dq = b ? qq : dq; vvv += b ? 1 : 0; }
        qq = dq * 2863311531u; { const bool b = qq <= 1431655765u; vvv += b ? 1 : 0; }
        vvv = (diff == 0u) ? 11 : vvv;
        const float2 wt = lut[vvv];  // (w, w*Pl)
        const float wS = wt.x * S;
        ws += wS; zz += wt.x; wpl += wt.y;
        cws[n] += wS; czz[n] += wt.x; cpl[n] += wt.y;
      }
      // row reduce across the 16 lanes holding this C-row (lane bits 0..3)
#pragma unroll
      for (int o = 1; o < 16; o <<= 1) {
        ws += __shfl_xor(ws, o, 64);
        zz += __shfl_xor(zz, o, 64);
        wpl += __shfl_xor(wpl, o, 64);
      }
      if (r0 == 0) {
        Pws[(size_t)dslot * N + i] = ws;
        Pz[(size_t)dslot * N + i] = zz;
        Ppl[(size_t)dslot * N + i] = wpl;
      }
    }
  }
  // transposed (column) partials -> rows of block jb, slot 2*ib+wr
  if (ib != jb) {
    const int tslot = ib * 2 + wr;
#pragma unroll
    for (int nn = 0; nn < 4; ++nn) {
      float a = cws[nn], b = czz[nn], c = cpl[nn];
#pragma unroll
      for (int o = 16; o < 64; o <<= 1) {
        a += __shfl_xor(a, o, 64);
        b += __shfl_xor(b, o, 64);
        c += __shfl_xor(c, o, 64);
      }
      if (kg == 0) {
        const int j = jbase + nn * 16;
        Pws[(size_t)tslot * N + j] = a;
        Pz[(size_t)tslot * N + j] = b;
        Ppl[(size_t)tslot * N + j] = c;
      }
    }
  }
}

// Per-row: combine the 128 j-partials (fixed order) -> T_i
__global__ __launch_bounds__(256) void r1_kernel(
    const float* __restrict__ Pws, const float* __restrict__ Pz,
    const float* __restrict__ Ppl, float* __restrict__ t) {
  const int row = blockIdx.x * 256 + threadIdx.x;
  float ws = 0.f, zz = 0.f, wpl = 0.f;
  for (int s = 0; s < 128; ++s) {
    ws += Pws[(size_t)s * N + row];
    zz += Pz[(size_t)s * N + row];
    wpl += Ppl[(size_t)s * N + row];
  }
  t[row] = (wpl - ws) / zz - logf(zz);
}

// Final deterministic scalar reduction.
__global__ __launch_bounds__(256) void r2_kernel(const float* __restrict__ t,
                                                 float* __restrict__ out) {
  __shared__ float red[256];
  float s = 0.f;
  for (int r = threadIdx.x; r < N; r += 256) s += t[r];
  red[threadIdx.x] = s;
  __syncthreads();
  for (int o = 128; o > 0; o >>= 1) {
    if (threadIdx.x < (unsigned)o) red[threadIdx.x] += red[threadIdx.x + o];
    __syncthreads();
  }
  if (threadIdx.x == 0) out[0] = red[0] / (float)N;
}

extern "C" void kernel_launch(void* const* d_in, const int* in_sizes, int n_in,
                              void* d_out, int out_size, void* d_ws, size_t ws_size,
                              hipStream_t stream) {
  const float* z = (const float*)d_in[0];
  const int* idx = (const int*)d_in[1];
  float* out = (float*)d_out;
  char* ws = (char*)d_ws;
  // workspace layout (~44.2 MB total); zh and zl MUST be adjacent (Kext view)
  unsigned short* zh = (unsigned short*)ws;                            // 16 MB
  unsigned short* zl = zh + (size_t)N * D;                             // 16 MB
  float* sq = (float*)(ws + ((size_t)32 << 20));                       // 32 KB
  float* Pws = (float*)(ws + ((size_t)32 << 20) + ((size_t)64 << 10)); // 4 MB
  float* Pz = Pws + (size_t)128 * N;                                   // 4 MB
  float* Ppl = Pz + (size_t)128 * N;                                   // 4 MB
  float* tt = Ppl + (size_t)128 * N;                                   // 32 KB

  prep_kernel<<<N, 256, 0, stream>>>(z, zh, zl, sq);
  gram_kernel<<<64 * 65 / 2, 256, 0, stream>>>(zh, sq, idx, Pws, Pz, Ppl);
  r1_kernel<<<N / 256, 256, 0, stream>>>(Pws, Pz, Ppl, tt);
  r2_kernel<<<1, 256, 0, stream>>>(tt, out);
}

// Round 12
// 249.702 us; speedup vs baseline: 1.5273x; 1.0328x over previous
//
#include <hip/hip_runtime.h>
#include <hip/hip_bf16.h>
#include <math.h>

#define GLOBAL_AS __attribute__((address_space(1)))
#define LDS_AS __attribute__((address_space(3)))

typedef __bf16 bf16x8 __attribute__((ext_vector_type(8)));
typedef float f32x4 __attribute__((ext_vector_type(4)));

#define N 8192
#define D 1024

__device__ __forceinline__ unsigned short f2bf_rne(float f) {
  unsigned u = __float_as_uint(f);
  unsigned r = u + 0x7FFFu + ((u >> 16) & 1u);
  return (unsigned short)(r >> 16);
}

// Convert z (fp32) -> z_hi + z_lo (bf16 split), and row sums of squares.
// zh and zl are adjacent: zl = zh + N*D, forming a [N][2048] "extended" bf16
// matrix whose gram = hi.hi + hi.lo + lo.hi + lo.lo ~= fp32 gram.
__global__ __launch_bounds__(256) void prep_kernel(
    const float* __restrict__ z, unsigned short* __restrict__ zh,
    unsigned short* __restrict__ zl, float* __restrict__ sq) {
  const int r = blockIdx.x, t = threadIdx.x;
  const float4 v = *(const float4*)(z + (size_t)r * D + t * 4);
  float f[4] = {v.x, v.y, v.z, v.w};
  unsigned short hh[4], ll[4];
  float s = 0.f;
#pragma unroll
  for (int u = 0; u < 4; ++u) {
    float x = f[u];
    s = fmaf(x, x, s);
    unsigned short hb = f2bf_rne(x);
    float hf = __uint_as_float(((unsigned)hb) << 16);
    hh[u] = hb;
    ll[u] = f2bf_rne(x - hf);
  }
  *(ushort4*)(zh + (size_t)r * D + t * 4) = make_ushort4(hh[0], hh[1], hh[2], hh[3]);
  *(ushort4*)(zl + (size_t)r * D + t * 4) = make_ushort4(ll[0], ll[1], ll[2], ll[3]);
  // deterministic block reduction
#pragma unroll
  for (int o = 32; o >= 1; o >>= 1) s += __shfl_down(s, o, 64);
  __shared__ float red[4];
  const int lane = t & 63, wv = t >> 6;
  if (lane == 0) red[wv] = s;
  __syncthreads();
  if (t == 0) sq[r] = ((red[0] + red[1]) + red[2]) + red[3];
}

// Lower-triangle 128x128 tile gram over Kext=2048, BK=128 single-buffer,
// fused KL epilogue.
//
// r6 vs r11 lesson: the 2-barrier structure pays a fixed stage+drain+barrier
// cost per k-step; r11 (BK=64, 32 MFMA/step, spill-free) = 241us while r6
// (3 blocks, spilling) = 223us -- the fix is fewer, fatter steps, not more
// blocks. BK=128: 16 steps x 64 MFMA (~310cy) per barrier pair, identical
// sync structure, SAME live set (a[4],b[4] reused per kc-quarter), and LDS
// 64KB caps us at 2 blocks/CU which the (256,2) reg budget gives anyway --
// unlike m132's BK=128 regression, nothing is lost.
//
// Swizzle (16 units/row): LDS unit (row, cs) holds global unit cs^(row&7);
// read unit ((kc<<2)|kg)^(r0&7) -> kc variants are byte-offset XOR
// 0/64/128/192; 8 distinct 16B slots per 16-lane group -> free 2-way.
__global__ __launch_bounds__(256, 2) void gram_kernel(
    const unsigned short* __restrict__ zh,
    const float* __restrict__ sq, const int* __restrict__ idx,
    float* __restrict__ Pws, float* __restrict__ Pz, float* __restrict__ Ppl) {
  __shared__ __align__(16) unsigned short lds[2 * 128 * 128];  // A, B (64 KiB)
  __shared__ float2 lut[12];  // (w, w*Pl) per v3 value; [11] = diff==0 case
  // triangle decode: blockIdx.x = ib*(ib+1)/2 + jb, jb <= ib
  const int t = blockIdx.x;
  int ibv = (int)((sqrtf(8.f * (float)t + 1.f) - 1.f) * 0.5f);
  while ((ibv + 1) * (ibv + 2) / 2 <= t) ++ibv;
  while (ibv * (ibv + 1) / 2 > t) --ibv;
  const int ib = __builtin_amdgcn_readfirstlane(ibv);
  const int jb = __builtin_amdgcn_readfirstlane(t - ibv * (ibv + 1) / 2);

  const int tid = threadIdx.x;
  const int lane = tid & 63, wv = tid >> 6;
  const int wr = wv >> 1, wc = wv & 1;
  const int r0 = lane & 15, kg = lane >> 4;

  if (tid < 12) {
    const float Pl = (tid == 11) ? 0.f : -2.f * exp2f(-1.5849625007211562f * (float)tid);
    const float w = exp2f(1.4426950408889634f * Pl);
    lut[tid] = make_float2(w, w * Pl);
  }

  // --- staging addressing ---
  // inst i8 covers tile rows i8*16+(tid>>4); unit col cs = tid&15; source
  // col unit = cs ^ (row&7) (row&7 == (tid>>4)&7 since i8*16 = 0 mod 8).
  const unsigned vstage =
      ((unsigned)(tid >> 4) * 2048u) + ((unsigned)((tid & 15) ^ ((tid >> 4) & 7)) * 16u);
  const char* aBase = (const char*)(zh + (size_t)ib * 128 * D);
  const char* bBase = (const char*)(zh + (size_t)jb * 128 * D);
  char* ldsc = (char*)&lds[0];

  // --- LDS read addressing; kc variant = base ^ (kc*64) ---
  const unsigned u0 = (unsigned)(kg ^ (r0 & 7));
  const unsigned aoff0 = (unsigned)((wr * 64 + r0) * 256) + u0 * 16u;
  const unsigned boff0 = 32768u + (unsigned)((wc * 64 + r0) * 256) + u0 * 16u;

  f32x4 acc[4][4];
  const f32x4 vz = {0.f, 0.f, 0.f, 0.f};
#pragma unroll
  for (int m = 0; m < 4; ++m)
#pragma unroll
    for (int n = 0; n < 4; ++n) acc[m][n] = vz;

  // Kext = 2048: two segments (hi, lo) x 8 steps of BK=128 (256B)
#pragma unroll 1
  for (int seg = 0; seg < 2; ++seg) {
    const size_t segoff = (size_t)seg * ((size_t)N * D * 2);
#pragma unroll 1
    for (int ks = 0; ks < 8; ++ks) {
      const char* aS = aBase + segoff + (unsigned)(ks * 256);
      const char* bS = bBase + segoff + (unsigned)(ks * 256);
      __syncthreads();
#pragma unroll
      for (int i8 = 0; i8 < 8; ++i8)
        __builtin_amdgcn_global_load_lds(
            (const GLOBAL_AS void*)(aS + (unsigned)(i8 * 32768) + vstage),
            (LDS_AS void*)(ldsc + i8 * 4096 + tid * 16), 16, 0, 0);
#pragma unroll
      for (int i8 = 0; i8 < 8; ++i8)
        __builtin_amdgcn_global_load_lds(
            (const GLOBAL_AS void*)(bS + (unsigned)(i8 * 32768) + vstage),
            (LDS_AS void*)(ldsc + 32768 + i8 * 4096 + tid * 16), 16, 0, 0);
      __syncthreads();

#pragma unroll
      for (int kc = 0; kc < 4; ++kc) {
        const unsigned ax = aoff0 ^ (unsigned)(kc * 64);
        const unsigned bx = boff0 ^ (unsigned)(kc * 64);
        bf16x8 a[4], b[4];
#pragma unroll
        for (int m = 0; m < 4; ++m) a[m] = *(const bf16x8*)(ldsc + ax + m * 4096);
#pragma unroll
        for (int n = 0; n < 4; ++n) b[n] = *(const bf16x8*)(ldsc + bx + n * 4096);
#pragma unroll
        for (int m = 0; m < 4; ++m)
#pragma unroll
          for (int n = 0; n < 4; ++n)
            acc[m][n] = __builtin_amdgcn_mfma_f32_16x16x32_bf16(a[m], b[n], acc[m][n], 0, 0, 0);
      }
    }
  }

  // ---- Epilogue: S = -2*sqrt(max(sq_i+sq_j-2g,0)); padic weights; partials ----
  const int ibase = ib * 128 + wr * 64 + kg * 4;
  const int jbase = jb * 128 + wc * 64 + r0;
  float sqj[4];
  int idxj[4];
#pragma unroll
  for (int n = 0; n < 4; ++n) {
    sqj[n] = sq[jbase + n * 16];
    idxj[n] = idx[jbase + n * 16];
  }
  const int dslot = jb * 2 + wc;
  // column (transposed) accumulators: per n, summed over this lane's (m,q) i-set
  float cws[4] = {0.f, 0.f, 0.f, 0.f};
  float czz[4] = {0.f, 0.f, 0.f, 0.f};
  float cpl[4] = {0.f, 0.f, 0.f, 0.f};
#pragma unroll
  for (int m = 0; m < 4; ++m) {
#pragma unroll
    for (int q = 0; q < 4; ++q) {
      const int i = ibase + m * 16 + q;
      const float sqi = sq[i];
      const int idxi = idx[i];
      float ws = 0.f, zz = 0.f, wpl = 0.f;
#pragma unroll
      for (int n = 0; n < 4; ++n) {
        const int j = jbase + n * 16;
        const float g = acc[m][n][q];
        const float d2 = sqi + sqj[n] - 2.f * g;
        const float dd = sqrtf(fmaxf(d2, 0.f));
        const float S = (i == j) ? 0.f : -2.f * dd;
        const int di = idxi - idxj[n];
        const unsigned diff = (unsigned)(di < 0 ? -di : di);
        // v3 via modular-inverse divisibility: /243(+5), /27(+3), /3(+1), /3(+1)
        unsigned dq = diff, qq;
        int vvv = 0;
        qq = dq * 3534952507u; { const bool b = qq <= 17674762u;   dq = b ? qq : dq; vvv += b ? 5 : 0; }
        qq = dq * 1749801491u; { const bool b = qq <= 159072862u;  dq = b ? qq : dq; vvv += b ? 3 : 0; }
        qq = dq * 2863311531u; { const bool b = qq <= 1431655765u; dq = b ? qq : dq; vvv += b ? 1 : 0; }
        qq = dq * 2863311531u; { const bool b = qq <= 1431655765u; vvv += b ? 1 : 0; }
        vvv = (diff == 0u) ? 11 : vvv;
        const float2 wt = lut[vvv];  // (w, w*Pl)
        const float wS = wt.x * S;
        ws += wS; zz += wt.x; wpl += wt.y;
        cws[n] += wS; czz[n] += wt.x; cpl[n] += wt.y;
      }
      // row reduce across the 16 lanes holding this C-row (lane bits 0..3)
#pragma unroll
      for (int o = 1; o < 16; o <<= 1) {
        ws += __shfl_xor(ws, o, 64);
        zz += __shfl_xor(zz, o, 64);
        wpl += __shfl_xor(wpl, o, 64);
      }
      if (r0 == 0) {
        Pws[(size_t)dslot * N + i] = ws;
        Pz[(size_t)dslot * N + i] = zz;
        Ppl[(size_t)dslot * N + i] = wpl;
      }
    }
  }
  // transposed (column) partials -> rows of block jb, slot 2*ib+wr
  if (ib != jb) {
    const int tslot = ib * 2 + wr;
#pragma unroll
    for (int nn = 0; nn < 4; ++nn) {
      float a = cws[nn], b = czz[nn], c = cpl[nn];
#pragma unroll
      for (int o = 16; o < 64; o <<= 1) {
        a += __shfl_xor(a, o, 64);
        b += __shfl_xor(b, o, 64);
        c += __shfl_xor(c, o, 64);
      }
      if (kg == 0) {
        const int j = jbase + nn * 16;
        Pws[(size_t)tslot * N + j] = a;
        Pz[(size_t)tslot * N + j] = b;
        Ppl[(size_t)tslot * N + j] = c;
      }
    }
  }
}

// Per-row: combine the 128 j-partials (fixed order) -> T_i
__global__ __launch_bounds__(256) void r1_kernel(
    const float* __restrict__ Pws, const float* __restrict__ Pz,
    const float* __restrict__ Ppl, float* __restrict__ t) {
  const int row = blockIdx.x * 256 + threadIdx.x;
  float ws = 0.f, zz = 0.f, wpl = 0.f;
  for (int s = 0; s < 128; ++s) {
    ws += Pws[(size_t)s * N + row];
    zz += Pz[(size_t)s * N + row];
    wpl += Ppl[(size_t)s * N + row];
  }
  t[row] = (wpl - ws) / zz - logf(zz);
}

// Final deterministic scalar reduction.
__global__ __launch_bounds__(256) void r2_kernel(const float* __restrict__ t,
                                                 float* __restrict__ out) {
  __shared__ float red[256];
  float s = 0.f;
  for (int r = threadIdx.x; r < N; r += 256) s += t[r];
  red[threadIdx.x] = s;
  __syncthreads();
  for (int o = 128; o > 0; o >>= 1) {
    if (threadIdx.x < (unsigned)o) red[threadIdx.x] += red[threadIdx.x + o];
    __syncthreads();
  }
  if (threadIdx.x == 0) out[0] = red[0] / (float)N;
}

extern "C" void kernel_launch(void* const* d_in, const int* in_sizes, int n_in,
                              void* d_out, int out_size, void* d_ws, size_t ws_size,
                              hipStream_t stream) {
  const float* z = (const float*)d_in[0];
  const int* idx = (const int*)d_in[1];
  float* out = (float*)d_out;
  char* ws = (char*)d_ws;
  // workspace layout (~44.2 MB total); zh and zl MUST be adjacent (Kext view)
  unsigned short* zh = (unsigned short*)ws;                            // 16 MB
  unsigned short* zl = zh + (size_t)N * D;                             // 16 MB
  float* sq = (float*)(ws + ((size_t)32 << 20));                       // 32 KB
  float* Pws = (float*)(ws + ((size_t)32 << 20) + ((size_t)64 << 10)); // 4 MB
  float* Pz = Pws + (size_t)128 * N;                                   // 4 MB
  float* Ppl = Pz + (size_t)128 * N;                                   // 4 MB
  float* tt = Ppl + (size_t)128 * N;                                   // 32 KB

  prep_kernel<<<N, 256, 0, stream>>>(z, zh, zl, sq);
  gram_kernel<<<64 * 65 / 2, 256, 0, stream>>>(zh, sq, idx, Pws, Pz, Ppl);
  r1_kernel<<<N / 256, 256, 0, stream>>>(Pws, Pz, Ppl, tt);
  r2_kernel<<<1, 256, 0, stream>>>(tt, out);
}

// Round 13
// 243.824 us; speedup vs baseline: 1.5641x; 1.0241x over previous
//
#include <hip/hip_runtime.h>
#include <hip/hip_bf16.h>
#include <math.h>

#define GLOBAL_AS __attribute__((address_space(1)))
#define LDS_AS __attribute__((address_space(3)))

typedef __bf16 bf16x8 __attribute__((ext_vector_type(8)));
typedef float f32x4 __attribute__((ext_vector_type(4)));

#define N 8192
#define D 1024

__device__ __forceinline__ unsigned short f2bf_rne(float f) {
  unsigned u = __float_as_uint(f);
  unsigned r = u + 0x7FFFu + ((u >> 16) & 1u);
  return (unsigned short)(r >> 16);
}

// Convert z (fp32) -> z_hi + z_lo (bf16 split), and row sums of squares.
// zh and zl are adjacent: zl = zh + N*D, forming a [N][2048] "extended" bf16
// matrix whose gram = hi.hi + hi.lo + lo.hi + lo.lo ~= fp32 gram.
__global__ __launch_bounds__(256) void prep_kernel(
    const float* __restrict__ z, unsigned short* __restrict__ zh,
    unsigned short* __restrict__ zl, float* __restrict__ sq) {
  const int r = blockIdx.x, t = threadIdx.x;
  const float4 v = *(const float4*)(z + (size_t)r * D + t * 4);
  float f[4] = {v.x, v.y, v.z, v.w};
  unsigned short hh[4], ll[4];
  float s = 0.f;
#pragma unroll
  for (int u = 0; u < 4; ++u) {
    float x = f[u];
    s = fmaf(x, x, s);
    unsigned short hb = f2bf_rne(x);
    float hf = __uint_as_float(((unsigned)hb) << 16);
    hh[u] = hb;
    ll[u] = f2bf_rne(x - hf);
  }
  *(ushort4*)(zh + (size_t)r * D + t * 4) = make_ushort4(hh[0], hh[1], hh[2], hh[3]);
  *(ushort4*)(zl + (size_t)r * D + t * 4) = make_ushort4(ll[0], ll[1], ll[2], ll[3]);
  // deterministic block reduction
#pragma unroll
  for (int o = 32; o >= 1; o >>= 1) s += __shfl_down(s, o, 64);
  __shared__ float red[4];
  const int lane = t & 63, wv = t >> 6;
  if (lane == 0) red[wv] = s;
  __syncthreads();
  if (t == 0) sq[r] = ((red[0] + red[1]) + red[2]) + red[3];
}

// Lower-triangle 128x128 tile gram over Kext=2048, BK=128 single-buffer,
// fused KL epilogue.
//
// r12 lesson: 3-bit swizzle on 16-unit (256B) rows left unit/unit+8 bank
// aliasing -> 1.7e7 conflict cycles (+4cy per ds_read_b128). Fix: full
// 4-bit swizzle, LDS unit = global_unit ^ (row&15) -> each 16-lane group
// reads 16 DISTINCT units = all 32 banks exactly once.
//
// Epilogue diet (r12: VALUBusy 33% > MfmaUtil 25%): (w, w*Pl) from a
// 243-entry LDS table indexed by diff%243 (umulhi magic, 3 VALU) instead
// of the 10-op v3 chain; rare diff%243==0 lanes (1/243) take a short
// fallback to the 12-entry LUT. Accumulate w*dd (sign folded into r1).
__global__ __launch_bounds__(256, 2) void gram_kernel(
    const unsigned short* __restrict__ zh,
    const float* __restrict__ sq, const int* __restrict__ idx,
    float* __restrict__ Pws, float* __restrict__ Pz, float* __restrict__ Ppl) {
  __shared__ __align__(16) unsigned short lds[2 * 128 * 128];  // A, B (64 KiB)
  __shared__ float2 w243[244];  // (w, w*Pl) by diff%243; [0] unused (branch)
  __shared__ float2 lut12[12];  // (w, w*Pl) by v3 value; [11] = diff==0
  // triangle decode: blockIdx.x = ib*(ib+1)/2 + jb, jb <= ib
  const int t = blockIdx.x;
  int ibv = (int)((sqrtf(8.f * (float)t + 1.f) - 1.f) * 0.5f);
  while ((ibv + 1) * (ibv + 2) / 2 <= t) ++ibv;
  while (ibv * (ibv + 1) / 2 > t) --ibv;
  const int ib = __builtin_amdgcn_readfirstlane(ibv);
  const int jb = __builtin_amdgcn_readfirstlane(t - ibv * (ibv + 1) / 2);

  const int tid = threadIdx.x;
  const int lane = tid & 63, wv = tid >> 6;
  const int wr = wv >> 1, wc = wv & 1;
  const int r0 = lane & 15, kg = lane >> 4;

  if (tid < 12) {
    const float Pl = (tid == 11) ? 0.f : -2.f * exp2f(-1.5849625007211562f * (float)tid);
    const float w = exp2f(1.4426950408889634f * Pl);
    lut12[tid] = make_float2(w, w * Pl);
  }
  if (tid < 243) {
    int rr = tid, v = 0;
    if (rr > 0) {
      while (rr % 3 == 0) { rr /= 3; ++v; }
    }
    const float Pl = -2.f * exp2f(-1.5849625007211562f * (float)v);
    const float w = exp2f(1.4426950408889634f * Pl);
    w243[tid] = make_float2(w, w * Pl);
  }

  // --- staging addressing (4-bit swizzle) ---
  // thread t covers row (t>>4) of each 16-row chunk, unit col cs = t&15;
  // source col unit = cs ^ (row&15). LDS dst linear (gload_lds rule).
  const unsigned vstage =
      ((unsigned)(tid >> 4) * 2048u) + ((unsigned)((tid & 15) ^ (tid >> 4)) * 16u);
  const char* aBase = (const char*)(zh + (size_t)ib * 128 * D);
  const char* bBase = (const char*)(zh + (size_t)jb * 128 * D);
  char* ldsc = (char*)&lds[0];

  // --- LDS read addressing; unit = (kc*4+kg) ^ (row&15), row&15 = r0 ---
  // byte form: u0 = kg^r0 (4 bits); kc variant = byte XOR kc*64 (bits 6-7).
  const unsigned u0 = (unsigned)((kg ^ r0) & 15);
  const unsigned aoff0 = (unsigned)((wr * 64 + r0) * 256) + u0 * 16u;
  const unsigned boff0 = 32768u + (unsigned)((wc * 64 + r0) * 256) + u0 * 16u;

  f32x4 acc[4][4];
  const f32x4 vz = {0.f, 0.f, 0.f, 0.f};
#pragma unroll
  for (int m = 0; m < 4; ++m)
#pragma unroll
    for (int n = 0; n < 4; ++n) acc[m][n] = vz;

  // Kext = 2048: two segments (hi, lo) x 8 steps of BK=128 (256B)
#pragma unroll 1
  for (int seg = 0; seg < 2; ++seg) {
    const size_t segoff = (size_t)seg * ((size_t)N * D * 2);
#pragma unroll 1
    for (int ks = 0; ks < 8; ++ks) {
      const char* aS = aBase + segoff + (unsigned)(ks * 256);
      const char* bS = bBase + segoff + (unsigned)(ks * 256);
      __syncthreads();
#pragma unroll
      for (int i8 = 0; i8 < 8; ++i8)
        __builtin_amdgcn_global_load_lds(
            (const GLOBAL_AS void*)(aS + (unsigned)(i8 * 32768) + vstage),
            (LDS_AS void*)(ldsc + i8 * 4096 + tid * 16), 16, 0, 0);
#pragma unroll
      for (int i8 = 0; i8 < 8; ++i8)
        __builtin_amdgcn_global_load_lds(
            (const GLOBAL_AS void*)(bS + (unsigned)(i8 * 32768) + vstage),
            (LDS_AS void*)(ldsc + 32768 + i8 * 4096 + tid * 16), 16, 0, 0);
      __syncthreads();

#pragma unroll
      for (int kc = 0; kc < 4; ++kc) {
        const unsigned ax = aoff0 ^ (unsigned)(kc * 64);
        const unsigned bx = boff0 ^ (unsigned)(kc * 64);
        bf16x8 a[4], b[4];
#pragma unroll
        for (int m = 0; m < 4; ++m) a[m] = *(const bf16x8*)(ldsc + ax + m * 4096);
#pragma unroll
        for (int n = 0; n < 4; ++n) b[n] = *(const bf16x8*)(ldsc + bx + n * 4096);
#pragma unroll
        for (int m = 0; m < 4; ++m)
#pragma unroll
          for (int n = 0; n < 4; ++n)
            acc[m][n] = __builtin_amdgcn_mfma_f32_16x16x32_bf16(a[m], b[n], acc[m][n], 0, 0, 0);
      }
    }
  }

  // ---- Epilogue: dd = sqrt(max(sq_i+sq_j-2g,0)); padic via mod-243 LUT ----
  // Accumulates ws = SUM w*dd (Sum w*S = -2*ws, folded into r1).
  const int ibase = ib * 128 + wr * 64 + kg * 4;
  const int jbase = jb * 128 + wc * 64 + r0;
  float sqj[4];
  int idxj[4];
#pragma unroll
  for (int n = 0; n < 4; ++n) {
    sqj[n] = sq[jbase + n * 16];
    idxj[n] = idx[jbase + n * 16];
  }
  const int dslot = jb * 2 + wc;
  // column (transposed) accumulators: per n, summed over this lane's (m,q) i-set
  float cws[4] = {0.f, 0.f, 0.f, 0.f};
  float czz[4] = {0.f, 0.f, 0.f, 0.f};
  float cpl[4] = {0.f, 0.f, 0.f, 0.f};
#pragma unroll
  for (int m = 0; m < 4; ++m) {
#pragma unroll
    for (int q = 0; q < 4; ++q) {
      const int i = ibase + m * 16 + q;
      const float sqi = sq[i];
      const int idxi = idx[i];
      float ws = 0.f, zz = 0.f, wpl = 0.f;
#pragma unroll
      for (int n = 0; n < 4; ++n) {
        const int j = jbase + n * 16;
        const float g = acc[m][n][q];
        const float d2 = sqi + sqj[n] - 2.f * g;
        const float dd = sqrtf(fmaxf(d2, 0.f));
        const int di = idxi - idxj[n];
        const unsigned diff = (unsigned)(di < 0 ? -di : di);
        // (w, w*Pl): table by diff%243 covers v3<5 (242/243 of pairs)
        const unsigned qd = __umulhi(diff, 17674763u);
        const unsigned rm = diff - qd * 243u;
        float2 wt = w243[rm];
        if (__builtin_expect(rm == 0u, 0)) {
          int vvv;
          if (diff == 0u) {
            vvv = 11;
          } else {  // v = 5 + v3(qd), qd in 1..242
            unsigned q2 = qd, t2;
            vvv = 5;
            t2 = q2 * 1749801491u; if (t2 <= 159072862u)  { q2 = t2; vvv += 3; }
            t2 = q2 * 2863311531u; if (t2 <= 1431655765u) { q2 = t2; vvv += 1; }
            t2 = q2 * 2863311531u; if (t2 <= 1431655765u) { vvv += 1; }
          }
          wt = lut12[vvv];
        }
        const float wdd = (i == j) ? 0.f : wt.x * dd;
        ws += wdd; zz += wt.x; wpl += wt.y;
        cws[n] += wdd; czz[n] += wt.x; cpl[n] += wt.y;
      }
      // row reduce across the 16 lanes holding this C-row (lane bits 0..3)
#pragma unroll
      for (int o = 1; o < 16; o <<= 1) {
        ws += __shfl_xor(ws, o, 64);
        zz += __shfl_xor(zz, o, 64);
        wpl += __shfl_xor(wpl, o, 64);
      }
      if (r0 == 0) {
        Pws[(size_t)dslot * N + i] = ws;
        Pz[(size_t)dslot * N + i] = zz;
        Ppl[(size_t)dslot * N + i] = wpl;
      }
    }
  }
  // transposed (column) partials -> rows of block jb, slot 2*ib+wr
  if (ib != jb) {
    const int tslot = ib * 2 + wr;
#pragma unroll
    for (int nn = 0; nn < 4; ++nn) {
      float a = cws[nn], b = czz[nn], c = cpl[nn];
#pragma unroll
      for (int o = 16; o < 64; o <<= 1) {
        a += __shfl_xor(a, o, 64);
        b += __shfl_xor(b, o, 64);
        c += __shfl_xor(c, o, 64);
      }
      if (kg == 0) {
        const int j = jbase + nn * 16;
        Pws[(size_t)tslot * N + j] = a;
        Pz[(size_t)tslot * N + j] = b;
        Ppl[(size_t)tslot * N + j] = c;
      }
    }
  }
}

// Per-row: combine the 128 j-partials (fixed order) -> T_i.
// Pws holds SUM w*dd; SUM w*S = -2*ws, so T = (wpl + 2*ws)/zz - log zz.
__global__ __launch_bounds__(256) void r1_kernel(
    const float* __restrict__ Pws, const float* __restrict__ Pz,
    const float* __restrict__ Ppl, float* __restrict__ t) {
  const int row = blockIdx.x * 256 + threadIdx.x;
  float ws = 0.f, zz = 0.f, wpl = 0.f;
  for (int s = 0; s < 128; ++s) {
    ws += Pws[(size_t)s * N + row];
    zz += Pz[(size_t)s * N + row];
    wpl += Ppl[(size_t)s * N + row];
  }
  t[row] = (wpl + 2.f * ws) / zz - logf(zz);
}

// Final deterministic scalar reduction.
__global__ __launch_bounds__(256) void r2_kernel(const float* __restrict__ t,
                                                 float* __restrict__ out) {
  __shared__ float red[256];
  float s = 0.f;
  for (int r = threadIdx.x; r < N; r += 256) s += t[r];
  red[threadIdx.x] = s;
  __syncthreads();
  for (int o = 128; o > 0; o >>= 1) {
    if (threadIdx.x < (unsigned)o) red[threadIdx.x] += red[threadIdx.x + o];
    __syncthreads();
  }
  if (threadIdx.x == 0) out[0] = red[0] / (float)N;
}

extern "C" void kernel_launch(void* const* d_in, const int* in_sizes, int n_in,
                              void* d_out, int out_size, void* d_ws, size_t ws_size,
                              hipStream_t stream) {
  const float* z = (const float*)d_in[0];
  const int* idx = (const int*)d_in[1];
  float* out = (float*)d_out;
  char* ws = (char*)d_ws;
  // workspace layout (~44.2 MB total); zh and zl MUST be adjacent (Kext view)
  unsigned short* zh = (unsigned short*)ws;                            // 16 MB
  unsigned short* zl = zh + (size_t)N * D;                             // 16 MB
  float* sq = (float*)(ws + ((size_t)32 << 20));                       // 32 KB
  float* Pws = (float*)(ws + ((size_t)32 << 20) + ((size_t)64 << 10)); // 4 MB
  float* Pz = Pws + (size_t)128 * N;                                   // 4 MB
  float* Ppl = Pz + (size_t)128 * N;                                   // 4 MB
  float* tt = Ppl + (size_t)128 * N;                                   // 32 KB

  prep_kernel<<<N, 256, 0, stream>>>(z, zh, zl, sq);
  gram_kernel<<<64 * 65 / 2, 256, 0, stream>>>(zh, sq, idx, Pws, Pz, Ppl);
  r1_kernel<<<N / 256, 256, 0, stream>>>(Pws, Pz, Ppl, tt);
  r2_kernel<<<1, 256, 0, stream>>>(tt, out);
}